// Round 6
// baseline (83.249 us; speedup 1.0000x reference)
//
#include <hip/hip_runtime.h>
#include <hip/hip_bf16.h>

#define BB 64
#define TT 256
#define HH 200
#define KK 48
#define AS 216          // LDS row stride (bf16 elems): 432B -> 2-way banks (free)

typedef __attribute__((ext_vector_type(8))) short bf16x8;
typedef __attribute__((ext_vector_type(4))) float f32x4;

static __device__ __forceinline__ unsigned short f2bf(float x) {
    __hip_bfloat16 h = __float2bfloat16(x);
    return *reinterpret_cast<unsigned short*>(&h);
}

// 1024 blocks x 256 threads. Block = (batch, 64-t tile); wave = 16-t slice, all 48 k.
// Swapped GEMM: D = W . feats^T -> lane 16*rg+cc holds em[k=q*16+rg*4+j][t=tb+cc].
__global__ __launch_bounds__(256)
void crf_one(const float* __restrict__ feats,
             const float* __restrict__ W_e,
             const float* __restrict__ b_e,
             const int*   __restrict__ targets,
             const int*   __restrict__ mask,
             const int*   __restrict__ end_tag_p,
             float*       __restrict__ out)
{
    __shared__ __align__(16) unsigned short Wlds[KK * AS];   // 20736 B

    const int tid  = threadIdx.x;
    const int lane = tid & 63;
    const int w    = tid >> 6;          // wave 0..3 -> 16-t slice
    const int bidx = blockIdx.x >> 2;   // batch
    const int tq   = blockIdx.x & 3;    // 64-t tile

    // ---- stage W: 48 x 200 f32 -> bf16 LDS (2400 float4 groups) ----
    {
        const float4* w4 = reinterpret_cast<const float4*>(W_e);
        for (int i = tid; i < KK * 50; i += 256) {
            const int r = i / 50, c = i - r * 50;
            const float4 v = w4[i];
            ushort4 o = { f2bf(v.x), f2bf(v.y), f2bf(v.z), f2bf(v.w) };
            *reinterpret_cast<ushort4*>(&Wlds[r * AS + c * 4]) = o;
        }
    }

    // ---- mask length (wave-redundant: 64 lanes x int4 = 256 ints) ----
    int len;
    {
        const int4 mv4 = reinterpret_cast<const int4*>(mask + bidx * TT)[lane];
        int mv = mv4.x + mv4.y + mv4.z + mv4.w;
        #pragma unroll
        for (int off = 32; off >= 1; off >>= 1) mv += __shfl_xor(mv, off);
        len = mv;
    }
    __syncthreads();

    const int rg = lane >> 4;           // k-slot group 0..3
    const int cc = lane & 15;           // t within slice / A-row within quarter
    const int tb = tq * 64 + w * 16;    // first t of this wave's slice
    const int gt = tb + cc;             // this lane's t

    const float* frow = feats + (size_t)(bidx * TT + gt) * HH;

    f32x4 ac0 = {0.f,0.f,0.f,0.f}, ac1 = {0.f,0.f,0.f,0.f}, ac2 = {0.f,0.f,0.f,0.f};

    #pragma unroll
    for (int kc = 0; kc < 7; ++kc) {
        const int h0 = kc * 32 + rg * 8;
        bf16x8 bfr, a0, a1, a2;
        if (kc < 6 || rg == 0) {        // h0+7 < 200 only then
            const float4 v0 = *reinterpret_cast<const float4*>(frow + h0);
            const float4 v1 = *reinterpret_cast<const float4*>(frow + h0 + 4);
            bfr[0]=(short)f2bf(v0.x); bfr[1]=(short)f2bf(v0.y);
            bfr[2]=(short)f2bf(v0.z); bfr[3]=(short)f2bf(v0.w);
            bfr[4]=(short)f2bf(v1.x); bfr[5]=(short)f2bf(v1.y);
            bfr[6]=(short)f2bf(v1.z); bfr[7]=(short)f2bf(v1.w);
            a0 = *reinterpret_cast<const bf16x8*>(&Wlds[( 0 + cc) * AS + h0]);
            a1 = *reinterpret_cast<const bf16x8*>(&Wlds[(16 + cc) * AS + h0]);
            a2 = *reinterpret_cast<const bf16x8*>(&Wlds[(32 + cc) * AS + h0]);
        } else {
            bfr = (bf16x8)(short)0; a0 = bfr; a1 = bfr; a2 = bfr;
        }
        ac0 = __builtin_amdgcn_mfma_f32_16x16x32_bf16(a0, bfr, ac0, 0, 0, 0);
        ac1 = __builtin_amdgcn_mfma_f32_16x16x32_bf16(a1, bfr, ac1, 0, 0, 0);
        ac2 = __builtin_amdgcn_mfma_f32_16x16x32_bf16(a2, bfr, ac2, 0, 0, 0);
    }

    // ---- epilogue: lane holds em[k=q*16+rg*4+j][t=gt], 12 values ----
    const float4 bq0 = *reinterpret_cast<const float4*>(b_e +  0 + rg * 4);
    const float4 bq1 = *reinterpret_cast<const float4*>(b_e + 16 + rg * 4);
    const float4 bq2 = *reinterpret_cast<const float4*>(b_e + 32 + rg * 4);
    float x[12];
    x[0]=ac0[0]+bq0.x; x[1]=ac0[1]+bq0.y; x[2] =ac0[2]+bq0.z; x[3] =ac0[3]+bq0.w;
    x[4]=ac1[0]+bq1.x; x[5]=ac1[1]+bq1.y; x[6] =ac1[2]+bq1.z; x[7] =ac1[3]+bq1.w;
    x[8]=ac2[0]+bq2.x; x[9]=ac2[1]+bq2.y; x[10]=ac2[2]+bq2.z; x[11]=ac2[3]+bq2.w;

    const int ET  = end_tag_p[0];
    const int tgt = targets[bidx * TT + gt] % KK;

    float m = x[0];
    #pragma unroll
    for (int i = 1; i < 12; ++i) m = fmaxf(m, x[i]);
    float s = 0.f, g = 0.f, e = 0.f;
    #pragma unroll
    for (int i = 0; i < 12; ++i) {
        s += expf(x[i] - m);
        const int q = i >> 2;                    // static after unroll
        const int kk = q * 16 + rg * 4 + (i & 3);
        g += (kk == tgt) ? x[i] : 0.f;
        e += (kk == ET)  ? x[i] : 0.f;
    }

    // merge 4 rg-groups (lanes xor 16, 32): LSE-merge + sums
    #pragma unroll
    for (int off = 16; off <= 32; off <<= 1) {
        const float om = __shfl_xor(m, off);
        const float os = __shfl_xor(s, off);
        const float nm = fmaxf(m, om);
        s = s * expf(m - nm) + os * expf(om - nm);
        m = nm;
        g += __shfl_xor(g, off);
        e += __shfl_xor(e, off);
    }
    const float lse = m + logf(s);

    float c = 0.0f;
    if (gt < len)          c -= g;
    if (gt == len - 1)     c += e;
    else if (gt < len - 1) c += lse;
    if (rg != 0) c = 0.0f;              // one copy per t

    #pragma unroll
    for (int off = 8; off >= 1; off >>= 1) c += __shfl_xor(c, off);
    c += __shfl_xor(c, 16); c += __shfl_xor(c, 32);   // fold the zeroed groups too
    if (lane == 0) atomicAdd(out + bidx, c);
}

extern "C" void kernel_launch(void* const* d_in, const int* in_sizes, int n_in,
                              void* d_out, int out_size, void* d_ws, size_t ws_size,
                              hipStream_t stream) {
    const float* feats   = (const float*)d_in[0];
    const float* W_e     = (const float*)d_in[1];
    const float* b_e     = (const float*)d_in[2];
    const int*   targets = (const int*)d_in[3];
    const int*   mask    = (const int*)d_in[4];
    const int*   et      = (const int*)d_in[6];
    float*       out     = (float*)d_out;

    hipMemsetAsync(out, 0, BB * sizeof(float), stream);
    crf_one<<<dim3(BB * 4), dim3(256), 0, stream>>>(
        feats, W_e, b_e, targets, mask, et, out);
}